// Round 7
// baseline (135.074 us; speedup 1.0000x reference)
//
#include <hip/hip_runtime.h>
#include <math.h>

#define N_TOK 512
#define DIM   128
#define KDIM  1024
#define EPSF  1e-14f

// ============ Kernel 1: fused projection (GEMM + bias + ELU) ============
// grid 256 = rowg(64 groups of 8 rows) x colsel(4: m=colsel>>1 picks mu/sg,
// ch=colsel&1 picks 64-col half). block 512.
// Thread: q=t&15 (col quad), rsub=t>>4: row=rsub&7, kq=rsub>>3 (K split 4).
// Each thread: 1 row x 4 cols x 256 k; cross-kq reduce in LDS.
// Also zeroes the `done` counter used by kernel 2's last-block finalize.
__global__ __launch_bounds__(512) void proj_fused(
    const float* __restrict__ token, const float* __restrict__ Wmu,
    const float* __restrict__ bmu, const float* __restrict__ Wsg,
    const float* __restrict__ bsg, float* __restrict__ mu,
    float* __restrict__ sg, float* __restrict__ iv, int* __restrict__ done)
{
    __shared__ float hs[8][KDIM];          // 32 KB relu'd token rows
    __shared__ float4 red[3][8][16];       // 6 KB cross-kq partials
    const int bid = blockIdx.x;
    const int t = threadIdx.x;
    if (bid == 0 && t == 0) *done = 0;     // reset for pair_final (ws poisoned)

    const int rowg = bid >> 2, colsel = bid & 3;
    const int m = colsel >> 1, ch = colsel & 1;

    // stage 8 rows (2048 float4) with relu, coalesced
    {
        const float4* src = (const float4*)(token + (size_t)rowg * 8 * KDIM);
        float4* dst = (float4*)&hs[0][0];
        #pragma unroll
        for (int r = 0; r < 4; ++r) {
            int idx = t + r * 512;
            float4 v = src[idx];
            v.x = fmaxf(v.x, 0.f); v.y = fmaxf(v.y, 0.f);
            v.z = fmaxf(v.z, 0.f); v.w = fmaxf(v.w, 0.f);
            dst[idx] = v;
        }
    }
    __syncthreads();

    const int q = t & 15, rsub = t >> 4;
    const int row = rsub & 7, kq = rsub >> 3;     // kq: 0..3 -> k slice of 256
    const int d = ch * 64 + q * 4;                // col within 128
    const float* __restrict__ W = (m ? Wsg : Wmu) + (size_t)(kq * 256) * DIM + d;
    const float4* hp = (const float4*)(&hs[row][kq * 256]);

    float4 acc = make_float4(0.f, 0.f, 0.f, 0.f);
    #pragma unroll 4
    for (int k4 = 0; k4 < 64; ++k4) {
        float4 h = hp[k4];                         // b128 broadcast per 16 lanes
        const float* wp = W + (size_t)(k4 * 4) * DIM;
        float4 w0 = *(const float4*)(wp);
        float4 w1 = *(const float4*)(wp + DIM);
        float4 w2 = *(const float4*)(wp + 2 * DIM);
        float4 w3 = *(const float4*)(wp + 3 * DIM);
        acc.x = fmaf(h.x, w0.x, acc.x); acc.y = fmaf(h.x, w0.y, acc.y);
        acc.z = fmaf(h.x, w0.z, acc.z); acc.w = fmaf(h.x, w0.w, acc.w);
        acc.x = fmaf(h.y, w1.x, acc.x); acc.y = fmaf(h.y, w1.y, acc.y);
        acc.z = fmaf(h.y, w1.z, acc.z); acc.w = fmaf(h.y, w1.w, acc.w);
        acc.x = fmaf(h.z, w2.x, acc.x); acc.y = fmaf(h.z, w2.y, acc.y);
        acc.z = fmaf(h.z, w2.z, acc.z); acc.w = fmaf(h.z, w2.w, acc.w);
        acc.x = fmaf(h.w, w3.x, acc.x); acc.y = fmaf(h.w, w3.y, acc.y);
        acc.z = fmaf(h.w, w3.z, acc.z); acc.w = fmaf(h.w, w3.w, acc.w);
    }

    if (kq > 0) red[kq - 1][row][q] = acc;
    __syncthreads();
    if (kq == 0) {
        float4 r0 = red[0][row][q], r1 = red[1][row][q], r2 = red[2][row][q];
        acc.x += r0.x + r1.x + r2.x; acc.y += r0.y + r1.y + r2.y;
        acc.z += r0.z + r1.z + r2.z; acc.w += r0.w + r1.w + r2.w;
        const int rowi = rowg * 8 + row;
        if (m == 0) {
            float4 b = *(const float4*)(bmu + d);
            acc.x += b.x; acc.y += b.y; acc.z += b.z; acc.w += b.w;
            *(float4*)(mu + (size_t)rowi * DIM + d) = acc;
        } else {
            float4 b = *(const float4*)(bsg + d);
            float x0 = acc.x + b.x, x1 = acc.y + b.y;
            float x2 = acc.z + b.z, x3 = acc.w + b.w;
            float4 e, vv;
            e.x = (x0 > 0.f ? x0 : expm1f(x0)) + 1.0f + EPSF;
            e.y = (x1 > 0.f ? x1 : expm1f(x1)) + 1.0f + EPSF;
            e.z = (x2 > 0.f ? x2 : expm1f(x2)) + 1.0f + EPSF;
            e.w = (x3 > 0.f ? x3 : expm1f(x3)) + 1.0f + EPSF;
            vv.x = 1.0f / e.x; vv.y = 1.0f / e.y;
            vv.z = 1.0f / e.z; vv.w = 1.0f / e.w;
            *(float4*)(sg + (size_t)rowi * DIM + d) = e;
            *(float4*)(iv + (size_t)rowi * DIM + d) = vv;
        }
    }
}

// ============ Kernel 2: pairwise sym-KL + last-block finalize ============
// grid 512 = ig(32 groups of 16 i-rows) x jg(16 groups of 32 j); block 256.
// j-side: LDS transposed sj[3][128][33]; i-side: global b128 broadcast.
// e_ij = exp(D - 0.5*acc), acc = sum_d [(s_j+dm^2)*v_i + (s_i+dm^2)*v_j].
// After writing gpart, the 512th-arriving block (device-scope atomic) does
// the deterministic final reduction and writes out[0].
__global__ __launch_bounds__(256) void pair_final(
    const float* __restrict__ mu, const float* __restrict__ sg,
    const float* __restrict__ iv, const int* __restrict__ labels,
    const int* __restrict__ mask, float* __restrict__ gpart,
    int* __restrict__ done, float* __restrict__ out)
{
    __shared__ float sj[3][DIM][33];       // 49.6 KB
    __shared__ int slab[16], svalid[16];
    __shared__ int slast;
    __shared__ float redL[4], redI[4];
    const int ig = blockIdx.x >> 4, jg = blockIdx.x & 15;
    const int i0 = ig * 16, j0 = jg * 32;
    const int t = threadIdx.x;

    // stage j-slice transposed: coalesced row-major reads, scatter [d][row]
    {
        float* sjf = &sj[0][0][0];
        #pragma unroll
        for (int rep = 0; rep < 4; ++rep) {
            int rem = t + rep * 256;           // 0..1023
            int row = rem >> 5, dq = rem & 31;
            size_t src = (size_t)(j0 + row) * DIM + dq * 4;
            int b = (dq * 4) * 33 + row;
            float4 v;
            v = *(const float4*)(mu + src);
            sjf[b] = v.x; sjf[b + 33] = v.y; sjf[b + 66] = v.z; sjf[b + 99] = v.w;
            v = *(const float4*)(sg + src);
            sjf[4224 + b] = v.x; sjf[4224 + b + 33] = v.y;
            sjf[4224 + b + 66] = v.z; sjf[4224 + b + 99] = v.w;
            v = *(const float4*)(iv + src);
            sjf[8448 + b] = v.x; sjf[8448 + b + 33] = v.y;
            sjf[8448 + b + 66] = v.z; sjf[8448 + b + 99] = v.w;
        }
    }
    if (t < 16) {
        int lab = labels[i0 + t];
        slab[t] = lab;
        svalid[t] = (mask[i0 + t] == 1 && lab > 0) ? 1 : 0;
    }
    __syncthreads();

    const int jl = t & 31, isub = t >> 5;
    const int ia = 2 * isub;               // even row; odd row = ia+1
    const int j = j0 + jl;
    const int labj = labels[j];
    const bool validj = (mask[j] == 1) && (labj > 0);

    const float* pm = mu + (size_t)(i0 + ia) * DIM;   // row ia; ib at +DIM
    const float* ps = sg + (size_t)(i0 + ia) * DIM;
    const float* pv = iv + (size_t)(i0 + ia) * DIM;

    float accA = 0.f, accB = 0.f;
    float mnA = 1e30f, mnB = 1e30f;

    #pragma unroll 4
    for (int q = 0; q < 32; ++q) {
        const int d0 = q * 4;
        float jm0 = sj[0][d0 + 0][jl], jm1 = sj[0][d0 + 1][jl];
        float jm2 = sj[0][d0 + 2][jl], jm3 = sj[0][d0 + 3][jl];
        float js0 = sj[1][d0 + 0][jl], js1 = sj[1][d0 + 1][jl];
        float js2 = sj[1][d0 + 2][jl], js3 = sj[1][d0 + 3][jl];
        float jv0 = sj[2][d0 + 0][jl], jv1 = sj[2][d0 + 1][jl];
        float jv2 = sj[2][d0 + 2][jl], jv3 = sj[2][d0 + 3][jl];

        float4 mA = *(const float4*)(pm + d0);
        float4 sA = *(const float4*)(ps + d0);
        float4 vA = *(const float4*)(pv + d0);
        float4 mB = *(const float4*)(pm + DIM + d0);
        float4 sB = *(const float4*)(ps + DIM + d0);
        float4 vB = *(const float4*)(pv + DIM + d0);

        float dm;
        dm = mA.x - jm0; accA = fmaf(fmaf(dm, dm, js0), vA.x, fmaf(fmaf(dm, dm, sA.x), jv0, accA)); mnA = fminf(mnA, fabsf(dm));
        dm = mA.y - jm1; accA = fmaf(fmaf(dm, dm, js1), vA.y, fmaf(fmaf(dm, dm, sA.y), jv1, accA)); mnA = fminf(mnA, fabsf(dm));
        dm = mA.z - jm2; accA = fmaf(fmaf(dm, dm, js2), vA.z, fmaf(fmaf(dm, dm, sA.z), jv2, accA)); mnA = fminf(mnA, fabsf(dm));
        dm = mA.w - jm3; accA = fmaf(fmaf(dm, dm, js3), vA.w, fmaf(fmaf(dm, dm, sA.w), jv3, accA)); mnA = fminf(mnA, fabsf(dm));

        dm = mB.x - jm0; accB = fmaf(fmaf(dm, dm, js0), vB.x, fmaf(fmaf(dm, dm, sB.x), jv0, accB)); mnB = fminf(mnB, fabsf(dm));
        dm = mB.y - jm1; accB = fmaf(fmaf(dm, dm, js1), vB.y, fmaf(fmaf(dm, dm, sB.y), jv1, accB)); mnB = fminf(mnB, fabsf(dm));
        dm = mB.z - jm2; accB = fmaf(fmaf(dm, dm, js2), vB.z, fmaf(fmaf(dm, dm, sB.z), jv2, accB)); mnB = fminf(mnB, fabsf(dm));
        dm = mB.w - jm3; accB = fmaf(fmaf(dm, dm, js3), vB.w, fmaf(fmaf(dm, dm, sB.w), jv3, accB)); mnB = fminf(mnB, fabsf(dm));
    }

    const int ib = ia + 1;
    float eA = expf(128.0f - 0.5f * accA);
    float eB = expf(128.0f - 0.5f * accB);
    bool pvA = validj && (svalid[ia] != 0) && (mnA != 0.0f);
    bool pvB = validj && (svalid[ib] != 0) && (mnB != 0.0f);
    bool smA = pvA && (labj == slab[ia]);
    bool smB = pvB && (labj == slab[ib]);
    float dA = pvA ? eA : 0.f, nA = smA ? eA : 0.f, cA = smA ? 1.f : 0.f;
    float dB = pvB ? eB : 0.f, nB = smB ? eB : 0.f, cB = smB ? 1.f : 0.f;

    #pragma unroll
    for (int m = 1; m < 32; m <<= 1) {
        cA += __shfl_xor(cA, m); nA += __shfl_xor(nA, m); dA += __shfl_xor(dA, m);
        cB += __shfl_xor(cB, m); nB += __shfl_xor(nB, m); dB += __shfl_xor(dB, m);
    }
    if (jl == 0) {
        float* pa = gpart + ((size_t)jg * N_TOK + i0 + ia) * 3;
        float* pb = gpart + ((size_t)jg * N_TOK + i0 + ib) * 3;
        pa[0] = cA; pa[1] = nA; pa[2] = dA;
        pb[0] = cB; pb[1] = nB; pb[2] = dB;
    }

    // -------- last-block finalize --------
    __threadfence();                        // release our gpart writes
    if (t == 0) slast = (atomicAdd(done, 1) == 511);
    __syncthreads();
    if (!slast) return;
    __threadfence();                        // acquire all gpart writes

    float lfs = 0.f, fis = 0.f;
    #pragma unroll
    for (int rr = 0; rr < 2; ++rr) {
        const int row = t + rr * 256;
        float c = 0.f, nm = 0.f, dn = 0.f;
        #pragma unroll
        for (int g = 0; g < 16; ++g) {
            const float* p = gpart + ((size_t)g * N_TOK + row) * 3;
            c += p[0]; nm += p[1]; dn += p[2];
        }
        if (c > 0.5f) {
            lfs += -logf(nm) + logf(dn) + logf(c);
            fis += 1.f;
        }
    }
    #pragma unroll
    for (int m = 1; m < 64; m <<= 1) {
        lfs += __shfl_xor(lfs, m);
        fis += __shfl_xor(fis, m);
    }
    if ((t & 63) == 0) { redL[t >> 6] = lfs; redI[t >> 6] = fis; }
    __syncthreads();
    if (t == 0) {
        float L = redL[0] + redL[1] + redL[2] + redL[3];
        float I = redI[0] + redI[1] + redI[2] + redI[3];
        out[0] = L / fmaxf(I, 1.0f);
    }
}

// ============ launcher ============
extern "C" void kernel_launch(void* const* d_in, const int* in_sizes, int n_in,
                              void* d_out, int out_size, void* d_ws, size_t ws_size,
                              hipStream_t stream) {
    const float* token  = (const float*)d_in[0];
    const int*   labels = (const int*)d_in[1];
    const int*   mask   = (const int*)d_in[2];
    const float* Wmu    = (const float*)d_in[3];
    const float* bmu    = (const float*)d_in[4];
    const float* Wsg    = (const float*)d_in[5];
    const float* bsg    = (const float*)d_in[6];

    float* ws = (float*)d_ws;
    float* mu    = ws;                        // 65,536
    float* sg    = mu + 65536;
    float* iv    = sg + 65536;
    float* gpart = iv + 65536;                // 16*512*3 = 24,576
    int*   done  = (int*)(gpart + 24576);

    proj_fused<<<256, 512, 0, stream>>>(token, Wmu, bmu, Wsg, bsg, mu, sg, iv, done);
    pair_final<<<512, 256, 0, stream>>>(mu, sg, iv, labels, mask, gpart, done,
                                        (float*)d_out);
}

// Round 8
// 106.458 us; speedup vs baseline: 1.2688x; 1.2688x over previous
//
#include <hip/hip_runtime.h>
#include <math.h>

#define N_TOK 512
#define DIM   128
#define KDIM  1024
#define EPSF  1e-14f

// ============ Kernel 1: fused projection (GEMM + bias + ELU) ============
// grid 256 = rowg(64 groups of 8 rows) x colsel(4: m=colsel>>1 picks mu/sg,
// ch=colsel&1 picks 64-col half). block 512.
// Thread: q=t&15 (col quad), rsub=t>>4: row=rsub&7, kq=rsub>>3 (K split 4).
// Each thread: 1 row x 4 cols x 256 k; cross-kq reduce in LDS.
__global__ __launch_bounds__(512) void proj_fused(
    const float* __restrict__ token, const float* __restrict__ Wmu,
    const float* __restrict__ bmu, const float* __restrict__ Wsg,
    const float* __restrict__ bsg, float* __restrict__ mu,
    float* __restrict__ sg, float* __restrict__ iv)
{
    __shared__ float hs[8][KDIM];          // 32 KB relu'd token rows
    __shared__ float4 red[3][8][16];       // 6 KB cross-kq partials
    const int bid = blockIdx.x;
    const int t = threadIdx.x;

    const int rowg = bid >> 2, colsel = bid & 3;
    const int m = colsel >> 1, ch = colsel & 1;

    // stage 8 rows (2048 float4) with relu, coalesced
    {
        const float4* src = (const float4*)(token + (size_t)rowg * 8 * KDIM);
        float4* dst = (float4*)&hs[0][0];
        #pragma unroll
        for (int r = 0; r < 4; ++r) {
            int idx = t + r * 512;
            float4 v = src[idx];
            v.x = fmaxf(v.x, 0.f); v.y = fmaxf(v.y, 0.f);
            v.z = fmaxf(v.z, 0.f); v.w = fmaxf(v.w, 0.f);
            dst[idx] = v;
        }
    }
    __syncthreads();

    const int q = t & 15, rsub = t >> 4;
    const int row = rsub & 7, kq = rsub >> 3;     // kq: 0..3 -> k slice of 256
    const int d = ch * 64 + q * 4;                // col within 128
    const float* __restrict__ W = (m ? Wsg : Wmu) + (size_t)(kq * 256) * DIM + d;
    const float4* hp = (const float4*)(&hs[row][kq * 256]);

    float4 acc = make_float4(0.f, 0.f, 0.f, 0.f);
    #pragma unroll 4
    for (int k4 = 0; k4 < 64; ++k4) {
        float4 h = hp[k4];                         // b128 broadcast per 16 lanes
        const float* wp = W + (size_t)(k4 * 4) * DIM;
        float4 w0 = *(const float4*)(wp);
        float4 w1 = *(const float4*)(wp + DIM);
        float4 w2 = *(const float4*)(wp + 2 * DIM);
        float4 w3 = *(const float4*)(wp + 3 * DIM);
        acc.x = fmaf(h.x, w0.x, acc.x); acc.y = fmaf(h.x, w0.y, acc.y);
        acc.z = fmaf(h.x, w0.z, acc.z); acc.w = fmaf(h.x, w0.w, acc.w);
        acc.x = fmaf(h.y, w1.x, acc.x); acc.y = fmaf(h.y, w1.y, acc.y);
        acc.z = fmaf(h.y, w1.z, acc.z); acc.w = fmaf(h.y, w1.w, acc.w);
        acc.x = fmaf(h.z, w2.x, acc.x); acc.y = fmaf(h.z, w2.y, acc.y);
        acc.z = fmaf(h.z, w2.z, acc.z); acc.w = fmaf(h.z, w2.w, acc.w);
        acc.x = fmaf(h.w, w3.x, acc.x); acc.y = fmaf(h.w, w3.y, acc.y);
        acc.z = fmaf(h.w, w3.z, acc.z); acc.w = fmaf(h.w, w3.w, acc.w);
    }

    if (kq > 0) red[kq - 1][row][q] = acc;
    __syncthreads();
    if (kq == 0) {
        float4 r0 = red[0][row][q], r1 = red[1][row][q], r2 = red[2][row][q];
        acc.x += r0.x + r1.x + r2.x; acc.y += r0.y + r1.y + r2.y;
        acc.z += r0.z + r1.z + r2.z; acc.w += r0.w + r1.w + r2.w;
        const int rowi = rowg * 8 + row;
        if (m == 0) {
            float4 b = *(const float4*)(bmu + d);
            acc.x += b.x; acc.y += b.y; acc.z += b.z; acc.w += b.w;
            *(float4*)(mu + (size_t)rowi * DIM + d) = acc;
        } else {
            float4 b = *(const float4*)(bsg + d);
            float x0 = acc.x + b.x, x1 = acc.y + b.y;
            float x2 = acc.z + b.z, x3 = acc.w + b.w;
            float4 e, vv;
            e.x = (x0 > 0.f ? x0 : expm1f(x0)) + 1.0f + EPSF;
            e.y = (x1 > 0.f ? x1 : expm1f(x1)) + 1.0f + EPSF;
            e.z = (x2 > 0.f ? x2 : expm1f(x2)) + 1.0f + EPSF;
            e.w = (x3 > 0.f ? x3 : expm1f(x3)) + 1.0f + EPSF;
            vv.x = 1.0f / e.x; vv.y = 1.0f / e.y;
            vv.z = 1.0f / e.z; vv.w = 1.0f / e.w;
            *(float4*)(sg + (size_t)rowi * DIM + d) = e;
            *(float4*)(iv + (size_t)rowi * DIM + d) = vv;
        }
    }
}

// ============ Kernel 2: pack transposed j-operand ============
// jpack[d][n] = (mu[n][d], sg[n][d], iv[n][d], 0).  grid 64 (8 rows), block 256.
__global__ __launch_bounds__(256) void packT(
    const float* __restrict__ mu, const float* __restrict__ sg,
    const float* __restrict__ iv, float4* __restrict__ jpack)
{
    __shared__ float tmu[8][132], tsg[8][132], tiv[8][132];
    const int rg = blockIdx.x;
    const int t = threadIdx.x;
    const int q = t & 31, r = t >> 5;      // q: d-quad (0..31), r: row (0..7)
    const int row = rg * 8 + r;
    const int d = q * 4;

    *(float4*)(&tmu[r][d]) = *(const float4*)(mu + (size_t)row * DIM + d);
    *(float4*)(&tsg[r][d]) = *(const float4*)(sg + (size_t)row * DIM + d);
    *(float4*)(&tiv[r][d]) = *(const float4*)(iv + (size_t)row * DIM + d);
    __syncthreads();

    // transposed packed write: thread -> (dd 0..127, rr in {0,4})
    const int dd = t >> 1, rr = (t & 1) * 4;
    #pragma unroll
    for (int k = 0; k < 4; ++k) {
        float4 o = make_float4(tmu[rr + k][dd], tsg[rr + k][dd], tiv[rr + k][dd], 0.f);
        jpack[(size_t)dd * N_TOK + rg * 8 + rr + k] = o;
    }
}

// ============ Kernel 3: pairwise sym-KL + masked row partial sums ==========
// (round-4 measured-good structure, verbatim)
// grid 512 = ig(32 groups of 16 i-rows) x jg(16 groups of 32 j); block 256.
// i-side: LDS row-major, broadcast b128. j-side: packed float4 per-lane
// coalesced loads (L1-resident).
// e_ij = exp(D - 0.5*acc), acc = sum_d [(s_j+dm^2)*v_i + (s_i+dm^2)*v_j].
__global__ __launch_bounds__(256) void pair_kernel(
    const float* __restrict__ mu, const float* __restrict__ sg,
    const float* __restrict__ iv, const float4* __restrict__ jpack,
    const int* __restrict__ labels, const int* __restrict__ mask,
    float* __restrict__ gpart)
{
    __shared__ float si[3][16][DIM];       // 24 KB
    __shared__ int slab[16], svalid[16];
    const int ig = blockIdx.x >> 4, jg = blockIdx.x & 15;
    const int i0 = ig * 16, j0 = jg * 32;
    const int t = threadIdx.x;

    #pragma unroll
    for (int rep = 0; rep < 2; ++rep) {
        int f = t + rep * 256;             // 0..511 float4 slots
        int row = f >> 5, kq = f & 31;
        size_t off = (size_t)(i0 + row) * DIM + kq * 4;
        ((float4*)&si[0][0][0])[f] = *(const float4*)(mu + off);
        ((float4*)&si[1][0][0])[f] = *(const float4*)(sg + off);
        ((float4*)&si[2][0][0])[f] = *(const float4*)(iv + off);
    }
    if (t < 16) {
        int lab = labels[i0 + t];
        slab[t] = lab;
        svalid[t] = (mask[i0 + t] == 1 && lab > 0) ? 1 : 0;
    }
    __syncthreads();

    const int jl = t & 31, isub = t >> 5;
    const int ia = 2 * isub, ib = ia + 1;
    const int j = j0 + jl;
    const int labj = labels[j];
    const bool validj = (mask[j] == 1) && (labj > 0);

    const float4* jp = jpack + j;

    float accA = 0.f, accB = 0.f;
    float mnA = 1e30f, mnB = 1e30f;

    #pragma unroll 4
    for (int q = 0; q < 32; ++q) {
        const int d0 = q * 4;
        float4 p0 = jp[(size_t)(d0 + 0) * N_TOK];   // (mu_j, sg_j, iv_j, 0)
        float4 p1 = jp[(size_t)(d0 + 1) * N_TOK];
        float4 p2 = jp[(size_t)(d0 + 2) * N_TOK];
        float4 p3 = jp[(size_t)(d0 + 3) * N_TOK];

        float4 bmA = *(const float4*)(&si[0][ia][d0]);
        float4 bsA = *(const float4*)(&si[1][ia][d0]);
        float4 bvA = *(const float4*)(&si[2][ia][d0]);
        float4 bmB = *(const float4*)(&si[0][ib][d0]);
        float4 bsB = *(const float4*)(&si[1][ib][d0]);
        float4 bvB = *(const float4*)(&si[2][ib][d0]);

        float dm;
        dm = bmA.x - p0.x; accA = fmaf(fmaf(dm, dm, p0.y), bvA.x, fmaf(fmaf(dm, dm, bsA.x), p0.z, accA)); mnA = fminf(mnA, fabsf(dm));
        dm = bmA.y - p1.x; accA = fmaf(fmaf(dm, dm, p1.y), bvA.y, fmaf(fmaf(dm, dm, bsA.y), p1.z, accA)); mnA = fminf(mnA, fabsf(dm));
        dm = bmA.z - p2.x; accA = fmaf(fmaf(dm, dm, p2.y), bvA.z, fmaf(fmaf(dm, dm, bsA.z), p2.z, accA)); mnA = fminf(mnA, fabsf(dm));
        dm = bmA.w - p3.x; accA = fmaf(fmaf(dm, dm, p3.y), bvA.w, fmaf(fmaf(dm, dm, bsA.w), p3.z, accA)); mnA = fminf(mnA, fabsf(dm));

        dm = bmB.x - p0.x; accB = fmaf(fmaf(dm, dm, p0.y), bvB.x, fmaf(fmaf(dm, dm, bsB.x), p0.z, accB)); mnB = fminf(mnB, fabsf(dm));
        dm = bmB.y - p1.x; accB = fmaf(fmaf(dm, dm, p1.y), bvB.y, fmaf(fmaf(dm, dm, bsB.y), p1.z, accB)); mnB = fminf(mnB, fabsf(dm));
        dm = bmB.z - p2.x; accB = fmaf(fmaf(dm, dm, p2.y), bvB.z, fmaf(fmaf(dm, dm, bsB.z), p2.z, accB)); mnB = fminf(mnB, fabsf(dm));
        dm = bmB.w - p3.x; accB = fmaf(fmaf(dm, dm, p3.y), bvB.w, fmaf(fmaf(dm, dm, bsB.w), p3.z, accB)); mnB = fminf(mnB, fabsf(dm));
    }

    float eA = expf(128.0f - 0.5f * accA);
    float eB = expf(128.0f - 0.5f * accB);
    bool pvA = validj && (svalid[ia] != 0) && (mnA != 0.0f);
    bool pvB = validj && (svalid[ib] != 0) && (mnB != 0.0f);
    bool smA = pvA && (labj == slab[ia]);
    bool smB = pvB && (labj == slab[ib]);
    float dA = pvA ? eA : 0.f, nA = smA ? eA : 0.f, cA = smA ? 1.f : 0.f;
    float dB = pvB ? eB : 0.f, nB = smB ? eB : 0.f, cB = smB ? 1.f : 0.f;

    // reduce over the 32 j-lanes (masks < 32 stay within half-wave)
    #pragma unroll
    for (int m = 1; m < 32; m <<= 1) {
        cA += __shfl_xor(cA, m); nA += __shfl_xor(nA, m); dA += __shfl_xor(dA, m);
        cB += __shfl_xor(cB, m); nB += __shfl_xor(nB, m); dB += __shfl_xor(dB, m);
    }
    if (jl == 0) {
        float* pa = gpart + ((size_t)jg * N_TOK + i0 + ia) * 3;
        float* pb = gpart + ((size_t)jg * N_TOK + i0 + ib) * 3;
        pa[0] = cA; pa[1] = nA; pa[2] = dA;
        pb[0] = cB; pb[1] = nB; pb[2] = dB;
    }
}

// ============ Kernel 4: final loss ============
__global__ __launch_bounds__(512) void final_kernel(
    const float* __restrict__ gpart, float* __restrict__ out)
{
    __shared__ float redL[8], redI[8];
    const int t = threadIdx.x;           // 512 threads = 512 rows
    float c = 0.f, nm = 0.f, dn = 0.f;
    #pragma unroll
    for (int jg = 0; jg < 16; ++jg) {
        const float* p = gpart + ((size_t)jg * N_TOK + t) * 3;
        c += p[0]; nm += p[1]; dn += p[2];
    }
    const bool inc = c > 0.5f;
    float lf = inc ? (-logf(nm) + logf(dn) + logf(c)) : 0.f;
    float fi = inc ? 1.f : 0.f;
    #pragma unroll
    for (int m = 1; m < 64; m <<= 1) {
        lf += __shfl_xor(lf, m);
        fi += __shfl_xor(fi, m);
    }
    if ((t & 63) == 0) { redL[t >> 6] = lf; redI[t >> 6] = fi; }
    __syncthreads();
    if (t == 0) {
        float L = 0.f, I = 0.f;
        #pragma unroll
        for (int w = 0; w < 8; ++w) { L += redL[w]; I += redI[w]; }
        out[0] = L / fmaxf(I, 1.0f);
    }
}

// ============ launcher ============
extern "C" void kernel_launch(void* const* d_in, const int* in_sizes, int n_in,
                              void* d_out, int out_size, void* d_ws, size_t ws_size,
                              hipStream_t stream) {
    const float* token  = (const float*)d_in[0];
    const int*   labels = (const int*)d_in[1];
    const int*   mask   = (const int*)d_in[2];
    const float* Wmu    = (const float*)d_in[3];
    const float* bmu    = (const float*)d_in[4];
    const float* Wsg    = (const float*)d_in[5];
    const float* bsg    = (const float*)d_in[6];

    float* ws = (float*)d_ws;
    float*  mu    = ws;                        // 65,536
    float*  sg    = mu + 65536;
    float*  iv    = sg + 65536;
    float4* jpack = (float4*)(iv + 65536);     // 128*512 float4
    float*  gpart = (float*)(jpack + 65536);   // 16*512*3 = 24,576
    // total: 4*65536 + 65536*4(float4 as floats... ) fits ws easily

    proj_fused<<<256, 512, 0, stream>>>(token, Wmu, bmu, Wsg, bsg, mu, sg, iv);
    packT<<<64, 256, 0, stream>>>(mu, sg, iv, jpack);
    pair_kernel<<<512, 256, 0, stream>>>(mu, sg, iv, jpack, labels, mask, gpart);
    final_kernel<<<1, 512, 0, stream>>>(gpart, (float*)d_out);
}

// Round 9
// 105.521 us; speedup vs baseline: 1.2801x; 1.0089x over previous
//
#include <hip/hip_runtime.h>
#include <math.h>

#define N_TOK 512
#define DIM   128
#define KDIM  1024
#define EPSF  1e-14f

// ============ Kernel 1: fused projection + transposed-operand write ========
// grid 256 = rowg(64 groups of 8 rows) x colsel(4: m=colsel>>1 picks mu/sg,
// ch=colsel&1 picks 64-col half). block 512.
// Thread: q=t&15 (col quad), rsub=t>>4: row=rsub&7, kq=rsub>>3 (K split 4).
// Each thread: 1 row x 4 cols x 256 k; cross-kq reduce in LDS.
// kq==0 threads also scatter transposed jmuT[d][n] / jsviT[d][n]=(sg,iv).
__global__ __launch_bounds__(512) void projT(
    const float* __restrict__ token, const float* __restrict__ Wmu,
    const float* __restrict__ bmu, const float* __restrict__ Wsg,
    const float* __restrict__ bsg, float* __restrict__ mu,
    float* __restrict__ sg, float* __restrict__ iv,
    float* __restrict__ jmuT, float2* __restrict__ jsviT)
{
    __shared__ float hs[8][KDIM];          // 32 KB relu'd token rows
    __shared__ float4 red[3][8][16];       // 6 KB cross-kq partials
    const int bid = blockIdx.x;
    const int t = threadIdx.x;

    const int rowg = bid >> 2, colsel = bid & 3;
    const int m = colsel >> 1, ch = colsel & 1;

    // stage 8 rows (2048 float4) with relu, coalesced
    {
        const float4* src = (const float4*)(token + (size_t)rowg * 8 * KDIM);
        float4* dst = (float4*)&hs[0][0];
        #pragma unroll
        for (int r = 0; r < 4; ++r) {
            int idx = t + r * 512;
            float4 v = src[idx];
            v.x = fmaxf(v.x, 0.f); v.y = fmaxf(v.y, 0.f);
            v.z = fmaxf(v.z, 0.f); v.w = fmaxf(v.w, 0.f);
            dst[idx] = v;
        }
    }
    __syncthreads();

    const int q = t & 15, rsub = t >> 4;
    const int row = rsub & 7, kq = rsub >> 3;     // kq: 0..3 -> k slice of 256
    const int d = ch * 64 + q * 4;                // col within 128
    const float* __restrict__ W = (m ? Wsg : Wmu) + (size_t)(kq * 256) * DIM + d;
    const float4* hp = (const float4*)(&hs[row][kq * 256]);

    float4 acc = make_float4(0.f, 0.f, 0.f, 0.f);
    #pragma unroll 4
    for (int k4 = 0; k4 < 64; ++k4) {
        float4 h = hp[k4];                         // b128 broadcast per 16 lanes
        const float* wp = W + (size_t)(k4 * 4) * DIM;
        float4 w0 = *(const float4*)(wp);
        float4 w1 = *(const float4*)(wp + DIM);
        float4 w2 = *(const float4*)(wp + 2 * DIM);
        float4 w3 = *(const float4*)(wp + 3 * DIM);
        acc.x = fmaf(h.x, w0.x, acc.x); acc.y = fmaf(h.x, w0.y, acc.y);
        acc.z = fmaf(h.x, w0.z, acc.z); acc.w = fmaf(h.x, w0.w, acc.w);
        acc.x = fmaf(h.y, w1.x, acc.x); acc.y = fmaf(h.y, w1.y, acc.y);
        acc.z = fmaf(h.y, w1.z, acc.z); acc.w = fmaf(h.y, w1.w, acc.w);
        acc.x = fmaf(h.z, w2.x, acc.x); acc.y = fmaf(h.z, w2.y, acc.y);
        acc.z = fmaf(h.z, w2.z, acc.z); acc.w = fmaf(h.z, w2.w, acc.w);
        acc.x = fmaf(h.w, w3.x, acc.x); acc.y = fmaf(h.w, w3.y, acc.y);
        acc.z = fmaf(h.w, w3.z, acc.z); acc.w = fmaf(h.w, w3.w, acc.w);
    }

    if (kq > 0) red[kq - 1][row][q] = acc;
    __syncthreads();
    if (kq == 0) {
        float4 r0 = red[0][row][q], r1 = red[1][row][q], r2 = red[2][row][q];
        acc.x += r0.x + r1.x + r2.x; acc.y += r0.y + r1.y + r2.y;
        acc.z += r0.z + r1.z + r2.z; acc.w += r0.w + r1.w + r2.w;
        const int rowi = rowg * 8 + row;
        if (m == 0) {
            float4 b = *(const float4*)(bmu + d);
            acc.x += b.x; acc.y += b.y; acc.z += b.z; acc.w += b.w;
            *(float4*)(mu + (size_t)rowi * DIM + d) = acc;
            // transposed scatter (4 scalar stores, 16B segments per 4 lanes)
            jmuT[(size_t)(d + 0) * N_TOK + rowi] = acc.x;
            jmuT[(size_t)(d + 1) * N_TOK + rowi] = acc.y;
            jmuT[(size_t)(d + 2) * N_TOK + rowi] = acc.z;
            jmuT[(size_t)(d + 3) * N_TOK + rowi] = acc.w;
        } else {
            float4 b = *(const float4*)(bsg + d);
            float x0 = acc.x + b.x, x1 = acc.y + b.y;
            float x2 = acc.z + b.z, x3 = acc.w + b.w;
            float4 e, vv;
            e.x = (x0 > 0.f ? x0 : expm1f(x0)) + 1.0f + EPSF;
            e.y = (x1 > 0.f ? x1 : expm1f(x1)) + 1.0f + EPSF;
            e.z = (x2 > 0.f ? x2 : expm1f(x2)) + 1.0f + EPSF;
            e.w = (x3 > 0.f ? x3 : expm1f(x3)) + 1.0f + EPSF;
            vv.x = 1.0f / e.x; vv.y = 1.0f / e.y;
            vv.z = 1.0f / e.z; vv.w = 1.0f / e.w;
            *(float4*)(sg + (size_t)rowi * DIM + d) = e;
            *(float4*)(iv + (size_t)rowi * DIM + d) = vv;
            jsviT[(size_t)(d + 0) * N_TOK + rowi] = make_float2(e.x, vv.x);
            jsviT[(size_t)(d + 1) * N_TOK + rowi] = make_float2(e.y, vv.y);
            jsviT[(size_t)(d + 2) * N_TOK + rowi] = make_float2(e.z, vv.z);
            jsviT[(size_t)(d + 3) * N_TOK + rowi] = make_float2(e.w, vv.w);
        }
    }
}

// ============ Kernel 2: pairwise sym-KL + masked row partial sums ==========
// grid 512 = ig(32 groups of 16 i-rows) x jg(16 groups of 32 j); block 256.
// i-side: LDS row-major, broadcast b128. j-side: transposed coalesced
// per-lane loads (jmuT scalar + jsviT float2, L1/L2-resident).
// e_ij = exp(D - 0.5*acc), acc = sum_d [(s_j+dm^2)*v_i + (s_i+dm^2)*v_j].
__global__ __launch_bounds__(256) void pair_kernel(
    const float* __restrict__ mu, const float* __restrict__ sg,
    const float* __restrict__ iv, const float* __restrict__ jmuT,
    const float2* __restrict__ jsviT, const int* __restrict__ labels,
    const int* __restrict__ mask, float* __restrict__ gpart)
{
    __shared__ float si[3][16][DIM];       // 24 KB
    __shared__ int slab[16], svalid[16];
    const int ig = blockIdx.x >> 4, jg = blockIdx.x & 15;
    const int i0 = ig * 16, j0 = jg * 32;
    const int t = threadIdx.x;

    #pragma unroll
    for (int rep = 0; rep < 2; ++rep) {
        int f = t + rep * 256;             // 0..511 float4 slots
        int row = f >> 5, kq = f & 31;
        size_t off = (size_t)(i0 + row) * DIM + kq * 4;
        ((float4*)&si[0][0][0])[f] = *(const float4*)(mu + off);
        ((float4*)&si[1][0][0])[f] = *(const float4*)(sg + off);
        ((float4*)&si[2][0][0])[f] = *(const float4*)(iv + off);
    }
    if (t < 16) {
        int lab = labels[i0 + t];
        slab[t] = lab;
        svalid[t] = (mask[i0 + t] == 1 && lab > 0) ? 1 : 0;
    }
    __syncthreads();

    const int jl = t & 31, isub = t >> 5;
    const int ia = 2 * isub, ib = ia + 1;
    const int j = j0 + jl;
    const int labj = labels[j];
    const bool validj = (mask[j] == 1) && (labj > 0);

    const float*  pmT = jmuT  + j;     // stride N_TOK per d
    const float2* psT = jsviT + j;

    float accA = 0.f, accB = 0.f;
    float mnA = 1e30f, mnB = 1e30f;

    #pragma unroll 4
    for (int q = 0; q < 32; ++q) {
        const int d0 = q * 4;
        float  jm0 = pmT[(size_t)(d0 + 0) * N_TOK];
        float  jm1 = pmT[(size_t)(d0 + 1) * N_TOK];
        float  jm2 = pmT[(size_t)(d0 + 2) * N_TOK];
        float  jm3 = pmT[(size_t)(d0 + 3) * N_TOK];
        float2 sv0 = psT[(size_t)(d0 + 0) * N_TOK];   // (sg_j, iv_j)
        float2 sv1 = psT[(size_t)(d0 + 1) * N_TOK];
        float2 sv2 = psT[(size_t)(d0 + 2) * N_TOK];
        float2 sv3 = psT[(size_t)(d0 + 3) * N_TOK];

        float4 bmA = *(const float4*)(&si[0][ia][d0]);
        float4 bsA = *(const float4*)(&si[1][ia][d0]);
        float4 bvA = *(const float4*)(&si[2][ia][d0]);
        float4 bmB = *(const float4*)(&si[0][ib][d0]);
        float4 bsB = *(const float4*)(&si[1][ib][d0]);
        float4 bvB = *(const float4*)(&si[2][ib][d0]);

        float dm;
        dm = bmA.x - jm0; accA = fmaf(fmaf(dm, dm, sv0.x), bvA.x, fmaf(fmaf(dm, dm, bsA.x), sv0.y, accA)); mnA = fminf(mnA, fabsf(dm));
        dm = bmA.y - jm1; accA = fmaf(fmaf(dm, dm, sv1.x), bvA.y, fmaf(fmaf(dm, dm, bsA.y), sv1.y, accA)); mnA = fminf(mnA, fabsf(dm));
        dm = bmA.z - jm2; accA = fmaf(fmaf(dm, dm, sv2.x), bvA.z, fmaf(fmaf(dm, dm, bsA.z), sv2.y, accA)); mnA = fminf(mnA, fabsf(dm));
        dm = bmA.w - jm3; accA = fmaf(fmaf(dm, dm, sv3.x), bvA.w, fmaf(fmaf(dm, dm, bsA.w), sv3.y, accA)); mnA = fminf(mnA, fabsf(dm));

        dm = bmB.x - jm0; accB = fmaf(fmaf(dm, dm, sv0.x), bvB.x, fmaf(fmaf(dm, dm, bsB.x), sv0.y, accB)); mnB = fminf(mnB, fabsf(dm));
        dm = bmB.y - jm1; accB = fmaf(fmaf(dm, dm, sv1.x), bvB.y, fmaf(fmaf(dm, dm, bsB.y), sv1.y, accB)); mnB = fminf(mnB, fabsf(dm));
        dm = bmB.z - jm2; accB = fmaf(fmaf(dm, dm, sv2.x), bvB.z, fmaf(fmaf(dm, dm, bsB.z), sv2.y, accB)); mnB = fminf(mnB, fabsf(dm));
        dm = bmB.w - jm3; accB = fmaf(fmaf(dm, dm, sv3.x), bvB.w, fmaf(fmaf(dm, dm, bsB.w), sv3.y, accB)); mnB = fminf(mnB, fabsf(dm));
    }

    float eA = expf(128.0f - 0.5f * accA);
    float eB = expf(128.0f - 0.5f * accB);
    bool pvA = validj && (svalid[ia] != 0) && (mnA != 0.0f);
    bool pvB = validj && (svalid[ib] != 0) && (mnB != 0.0f);
    bool smA = pvA && (labj == slab[ia]);
    bool smB = pvB && (labj == slab[ib]);
    float dA = pvA ? eA : 0.f, nA = smA ? eA : 0.f, cA = smA ? 1.f : 0.f;
    float dB = pvB ? eB : 0.f, nB = smB ? eB : 0.f, cB = smB ? 1.f : 0.f;

    // reduce over the 32 j-lanes (masks < 32 stay within half-wave)
    #pragma unroll
    for (int m = 1; m < 32; m <<= 1) {
        cA += __shfl_xor(cA, m); nA += __shfl_xor(nA, m); dA += __shfl_xor(dA, m);
        cB += __shfl_xor(cB, m); nB += __shfl_xor(nB, m); dB += __shfl_xor(dB, m);
    }
    if (jl == 0) {
        float* pa = gpart + ((size_t)jg * N_TOK + i0 + ia) * 3;
        float* pb = gpart + ((size_t)jg * N_TOK + i0 + ib) * 3;
        pa[0] = cA; pa[1] = nA; pa[2] = dA;
        pb[0] = cB; pb[1] = nB; pb[2] = dB;
    }
}

// ============ Kernel 3: final loss ============
__global__ __launch_bounds__(512) void final_kernel(
    const float* __restrict__ gpart, float* __restrict__ out)
{
    __shared__ float redL[8], redI[8];
    const int t = threadIdx.x;           // 512 threads = 512 rows
    float c = 0.f, nm = 0.f, dn = 0.f;
    #pragma unroll
    for (int jg = 0; jg < 16; ++jg) {
        const float* p = gpart + ((size_t)jg * N_TOK + t) * 3;
        c += p[0]; nm += p[1]; dn += p[2];
    }
    const bool inc = c > 0.5f;
    float lf = inc ? (-logf(nm) + logf(dn) + logf(c)) : 0.f;
    float fi = inc ? 1.f : 0.f;
    #pragma unroll
    for (int m = 1; m < 64; m <<= 1) {
        lf += __shfl_xor(lf, m);
        fi += __shfl_xor(fi, m);
    }
    if ((t & 63) == 0) { redL[t >> 6] = lf; redI[t >> 6] = fi; }
    __syncthreads();
    if (t == 0) {
        float L = 0.f, I = 0.f;
        #pragma unroll
        for (int w = 0; w < 8; ++w) { L += redL[w]; I += redI[w]; }
        out[0] = L / fmaxf(I, 1.0f);
    }
}

// ============ launcher ============
extern "C" void kernel_launch(void* const* d_in, const int* in_sizes, int n_in,
                              void* d_out, int out_size, void* d_ws, size_t ws_size,
                              hipStream_t stream) {
    const float* token  = (const float*)d_in[0];
    const int*   labels = (const int*)d_in[1];
    const int*   mask   = (const int*)d_in[2];
    const float* Wmu    = (const float*)d_in[3];
    const float* bmu    = (const float*)d_in[4];
    const float* Wsg    = (const float*)d_in[5];
    const float* bsg    = (const float*)d_in[6];

    float*  ws    = (float*)d_ws;
    float*  mu    = ws;                        // 65,536
    float*  sg    = mu + 65536;
    float*  iv    = sg + 65536;
    float*  jmuT  = iv + 65536;                // 65,536
    float2* jsviT = (float2*)(jmuT + 65536);   // 65,536 float2
    float*  gpart = (float*)(jsviT + 65536);   // 16*512*3 = 24,576

    projT<<<256, 512, 0, stream>>>(token, Wmu, bmu, Wsg, bsg, mu, sg, iv,
                                   jmuT, jsviT);
    pair_kernel<<<512, 256, 0, stream>>>(mu, sg, iv, jmuT, jsviT, labels, mask,
                                         gpart);
    final_kernel<<<1, 512, 0, stream>>>(gpart, (float*)d_out);
}